// Round 1
// baseline (134160.620 us; speedup 1.0000x reference)
//
#include <hip/hip_runtime.h>
#include <stdint.h>
#include <math.h>

// Persistent barrier-free 2-layer LSTM policy rollout on MI355X.
// 512 WGs x 128 threads; WG w owns h-units {2w, 2w+1} of both layers.
// Weights live in LDS as f16; h vectors are exchanged via 8-byte
// {fp32 value | uint32 step-tag} relaxed agent-scope atomics (no barriers).

#define H      1024
#define NSTEP  8192
#define NWG    512
#define BLK    128

typedef _Float16 h2 __attribute__((ext_vector_type(2)));

__device__ __forceinline__ unsigned long long pack_vt(float v, uint32_t tag){
  return ((unsigned long long)tag << 32) | (unsigned long long)__float_as_uint(v);
}

// Exact JAX threefry2x32 (5 blocks of 4 rounds).
__device__ __forceinline__ uint2 tf2x32(uint32_t k0, uint32_t k1, uint32_t x0, uint32_t x1){
  uint32_t k2 = k0 ^ k1 ^ 0x1BD11BDAu;
  x0 += k0; x1 += k1;
#define TFR(r) { x0 += x1; x1 = (x1 << (r)) | (x1 >> (32 - (r))); x1 ^= x0; }
  TFR(13) TFR(15) TFR(26) TFR(6)
  x0 += k1; x1 += k2 + 1u;
  TFR(17) TFR(29) TFR(16) TFR(24)
  x0 += k2; x1 += k0 + 2u;
  TFR(13) TFR(15) TFR(26) TFR(6)
  x0 += k0; x1 += k1 + 3u;
  TFR(17) TFR(29) TFR(16) TFR(24)
  x0 += k1; x1 += k2 + 4u;
  TFR(13) TFR(15) TFR(26) TFR(6)
  x0 += k2; x1 += k0 + 5u;
#undef TFR
  uint2 r; r.x = x0; r.y = x1; return r;
}

// keys = threefry_split(key(42), 8192): counts = iota(16384) split as (i, i+8192).
__device__ __forceinline__ uint32_t jax_word(uint32_t i){
  return (i < 8192u) ? tf2x32(0u, 42u, i, i + 8192u).x
                     : tf2x32(0u, 42u, i - 8192u, i).y;
}

__device__ __forceinline__ float wred64(float x){
  #pragma unroll
  for(int off = 32; off > 0; off >>= 1) x += __shfl_xor(x, off, 64);
  return x;
}

#if __has_builtin(__builtin_amdgcn_fdot2)
__device__ __forceinline__ float fdot2f(h2 a, h2 b, float c){ return __builtin_amdgcn_fdot2(a, b, c, false); }
#else
__device__ __forceinline__ float fdot2f(h2 a, h2 b, float c){
  return (float)a.x * (float)b.x + (float)a.y * (float)b.y + c;
}
#endif

__device__ __forceinline__ float sigm(float x){
  x = fminf(fmaxf(x, -30.f), 30.f);
  return 1.f / (1.f + __expf(-x));
}
__device__ __forceinline__ float tanh_f(float x){
  x = fminf(fmaxf(x, -15.f), 15.f);
  float e = __expf(2.f * x);
  return (e - 1.f) / (e + 1.f);
}

__device__ __forceinline__ void poll_stage(const unsigned long long* __restrict__ buf,
                                           uint32_t tag, h2* hsl, int tid){
  const int pb = tid << 3;           // 8 slots per thread
  unsigned long long pv[8];
  #pragma unroll
  for(int k = 0; k < 8; k++)
    pv[k] = __hip_atomic_load((unsigned long long*)&buf[pb + k], __ATOMIC_RELAXED, __HIP_MEMORY_SCOPE_AGENT);
  #pragma unroll
  for(int k = 0; k < 8; k++){
    while((uint32_t)(pv[k] >> 32) != tag){
      __builtin_amdgcn_s_sleep(1);
      pv[k] = __hip_atomic_load((unsigned long long*)&buf[pb + k], __ATOMIC_RELAXED, __HIP_MEMORY_SCOPE_AGENT);
    }
  }
  #pragma unroll
  for(int q = 0; q < 4; q++){
    h2 hp;
    hp.x = (_Float16)__uint_as_float((uint32_t)pv[2*q]);
    hp.y = (_Float16)__uint_as_float((uint32_t)pv[2*q + 1]);
    hsl[(tid << 2) + q] = hp;
  }
}

__global__ void __launch_bounds__(BLK)
lstm_persist(const float* __restrict__ ctx,  const float* __restrict__ W1p,  const float* __restrict__ b1p,
             const float* __restrict__ Wih0, const float* __restrict__ Whh0,
             const float* __restrict__ bih0, const float* __restrict__ bhh0,
             const float* __restrict__ Wih1, const float* __restrict__ Whh1,
             const float* __restrict__ bih1, const float* __restrict__ bhh1,
             const float* __restrict__ W2p,  const float* __restrict__ b2p,
             float* __restrict__ out,
             unsigned long long* __restrict__ h0buf,
             unsigned long long* __restrict__ h1buf)
{
  // LDS: 32KB + 16KB + 2KB + 2KB = 52KB -> 3 blocks/CU by LDS, co-residency OK.
  __shared__ h2 wA[16][H/2];  // rows [wv*8 + r]: r<4 Wih1 gate r of unit je; r>=4 Whh0 gate r-4
  __shared__ h2 wB[8][H/2];   // rows [wv*4 + g]: Whh1 gate g of unit je
  __shared__ h2 w2s[H/2];     // full W2 row (redundant per WG)
  __shared__ h2 hs[H/2];      // staged broadcast vector (f16)

  const int tid  = threadIdx.x;
  const int wg   = blockIdx.x;
  const int wv   = tid >> 6;
  const int lane = tid & 63;
  const int je   = (wg << 1) + wv;   // this wave's h-unit

  // ---- one-time: stage f16 weights into LDS (coalesced float2 reads)
  #pragma unroll 1
  for(int rr = 0; rr < 16; rr++){
    const int e = rr >> 3, pg = rr & 7;
    const int j = (wg << 1) + e;
    const float2* s2 = (const float2*)((pg < 4) ? (Wih1 + (size_t)(pg*H + j)*H)
                                                : (Whh0 + (size_t)((pg-4)*H + j)*H));
    for(int c = tid; c < H/2; c += BLK){
      float2 f = s2[c]; h2 p; p.x = (_Float16)f.x; p.y = (_Float16)f.y; wA[rr][c] = p;
    }
  }
  #pragma unroll 1
  for(int rr = 0; rr < 8; rr++){
    const int e = rr >> 2, g = rr & 3;
    const int j = (wg << 1) + e;
    const float2* s2 = (const float2*)(Whh1 + (size_t)(g*H + j)*H);
    for(int c = tid; c < H/2; c += BLK){
      float2 f = s2[c]; h2 p; p.x = (_Float16)f.x; p.y = (_Float16)f.y; wB[rr][c] = p;
    }
  }
  {
    const float2* s2 = (const float2*)W2p;
    for(int c = tid; c < H/2; c += BLK){
      float2 f = s2[c]; h2 p; p.x = (_Float16)f.x; p.y = (_Float16)f.y; w2s[c] = p;
    }
  }

  // per-wave scalar params (uniform across lanes)
  float b0g[4], b1g[4], w0g[4];
  #pragma unroll
  for(int g = 0; g < 4; g++){
    b0g[g] = bih0[g*H + je] + bhh0[g*H + je];
    b1g[g] = bih1[g*H + je] + bhh1[g*H + je];
    w0g[g] = Wih0[g*H + je];
  }
  const float b2v = b2p[0];

  // x0 = W1 @ context + b1 (redundant per wave)
  float xacc = 0.f;
  for(int c = lane; c < 512; c += 64) xacc += W1p[c] * ctx[c];
  const float x0 = wred64(xacc) + b1p[0];

  // state
  float c0 = 0.f, c1 = 0.f, logp = 0.f;
  float a0[4];                 // Whh0 @ h0(t)   rows for unit je (filled each P1)
  float a1[4] = {0.f,0.f,0.f,0.f}; // Whh1 @ h1(t-1) rows (zero at t=0)

  // h0(0) from x0 (c0 starts at 0)
  {
    float gi = sigm (w0g[0]*x0 + b0g[0]);
    float gf = sigm (w0g[1]*x0 + b0g[1]);
    float gg = tanh_f(w0g[2]*x0 + b0g[2]);
    float go = sigm (w0g[3]*x0 + b0g[3]);
    c0 = gi * gg;  // f*0 + i*g
    float h0v = go * tanh_f(c0);
    if(lane == 0)
      __hip_atomic_store(&h0buf[je], pack_vt(h0v, 1u), __ATOMIC_RELAXED, __HIP_MEMORY_SCOPE_AGENT);
  }
  __syncthreads();

  #pragma unroll 1
  for(int t = 0; t < NSTEP; t++){
    const uint32_t tt = (uint32_t)t;

    // RNG for this step depends only on t -> off the critical path
    const uint32_t kk0 = jax_word(2u*tt), kk1 = jax_word(2u*tt + 1u);
    const uint32_t bits = tf2x32(kk0, kk1, 0u, 0u).x;
    const float u = __uint_as_float((bits >> 9) | 0x3f800000u) - 1.0f;

    // ---------- P1: consume h0(t) ----------
    poll_stage(h0buf, tt + 1u, &hs[0], tid);
    __syncthreads();

    h2 hv[8];
    #pragma unroll
    for(int k = 0; k < 8; k++) hv[k] = hs[(lane << 3) + k];

    float sums[8];
    #pragma unroll
    for(int r = 0; r < 8; r++){
      const h2* wp = &wA[(wv << 3) + r][0];
      float acc0 = 0.f, acc1 = 0.f;
      #pragma unroll
      for(int k = 0; k < 4; k++) acc0 = fdot2f(wp[(lane << 3) + k], hv[k], acc0);
      #pragma unroll
      for(int k = 4; k < 8; k++) acc1 = fdot2f(wp[(lane << 3) + k], hv[k], acc1);
      sums[r] = wred64(acc0 + acc1);
    }
    // layer-1 cell (uniform on all lanes)
    {
      float gi = sigm (sums[0] + a1[0] + b1g[0]);
      float gf = sigm (sums[1] + a1[1] + b1g[1]);
      float gg = tanh_f(sums[2] + a1[2] + b1g[2]);
      float go = sigm (sums[3] + a1[3] + b1g[3]);
      c1 = gf*c1 + gi*gg;
      float h1v = go * tanh_f(c1);
      if(lane == 0)
        __hip_atomic_store(&h1buf[je], pack_vt(h1v, tt + 1u), __ATOMIC_RELAXED, __HIP_MEMORY_SCOPE_AGENT);
    }
    a0[0] = sums[4]; a0[1] = sums[5]; a0[2] = sums[6]; a0[3] = sums[7];
    __syncthreads();  // both waves done reading hs before restaging

    // ---------- P2: consume h1(t) ----------
    poll_stage(h1buf, tt + 1u, &hs[0], tid);
    __syncthreads();

    #pragma unroll
    for(int k = 0; k < 8; k++) hv[k] = hs[(lane << 3) + k];

    float s2r[4];
    #pragma unroll
    for(int r = 0; r < 4; r++){
      const h2* wp = &wB[(wv << 2) + r][0];
      float acc0 = 0.f, acc1 = 0.f;
      #pragma unroll
      for(int k = 0; k < 4; k++) acc0 = fdot2f(wp[(lane << 3) + k], hv[k], acc0);
      #pragma unroll
      for(int k = 4; k < 8; k++) acc1 = fdot2f(wp[(lane << 3) + k], hv[k], acc1);
      s2r[r] = wred64(acc0 + acc1);
    }
    float zacc = 0.f;
    #pragma unroll
    for(int k = 0; k < 8; k++) zacc = fdot2f(w2s[(lane << 3) + k], hv[k], zacc);
    const float z = wred64(zacc) + b2v;
    a1[0] = s2r[0]; a1[1] = s2r[1]; a1[2] = s2r[2]; a1[3] = s2r[3];

    // p, sample (bit-exact threefry), logp — redundant on every wave
    const float p = sigm(z);
    const float s = (u < p) ? 1.f : 0.f;
    logp += s * __logf(p) + (1.f - s) * __logf(1.f - p);
    if(wg == 0 && tid == 0) out[t] = s;

    // layer-0 cell -> h0(t+1)
    {
      float gi = sigm (a0[0] + w0g[0]*s + b0g[0]);
      float gf = sigm (a0[1] + w0g[1]*s + b0g[1]);
      float gg = tanh_f(a0[2] + w0g[2]*s + b0g[2]);
      float go = sigm (a0[3] + w0g[3]*s + b0g[3]);
      c0 = gf*c0 + gi*gg;
      float h0v = go * tanh_f(c0);
      if(lane == 0)
        __hip_atomic_store(&h0buf[je], pack_vt(h0v, tt + 2u), __ATOMIC_RELAXED, __HIP_MEMORY_SCOPE_AGENT);
    }
    __syncthreads();  // protect hs reuse by next P1
  }

  if(wg == 0 && tid == 0) out[NSTEP] = logp;
}

extern "C" void kernel_launch(void* const* d_in, const int* in_sizes, int n_in,
                              void* d_out, int out_size, void* d_ws, size_t ws_size,
                              hipStream_t stream){
  unsigned long long* h0buf = (unsigned long long*)d_ws;       // 1024 slots
  unsigned long long* h1buf = h0buf + H;                       // 1024 slots
  hipLaunchKernelGGL(lstm_persist, dim3(NWG), dim3(BLK), 0, stream,
    (const float*)d_in[0],  (const float*)d_in[1],  (const float*)d_in[2],
    (const float*)d_in[3],  (const float*)d_in[4],  (const float*)d_in[5],  (const float*)d_in[6],
    (const float*)d_in[7],  (const float*)d_in[8],  (const float*)d_in[9],  (const float*)d_in[10],
    (const float*)d_in[11], (const float*)d_in[12],
    (float*)d_out, h0buf, h1buf);
}